// Round 7
// baseline (1708.972 us; speedup 1.0000x reference)
//
#include <hip/hip_runtime.h>
#include <hip/hip_cooperative_groups.h>
#include <math.h>

namespace cg = cooperative_groups;

#define N_NODES 4096
#define NROWS   8192      // both sides stacked
#define BGRAPH  32
#define NEDGE   65536
#define DIM     128
#define NLAYER  4
#define NHEAD   4
#define DHEAD   32
#define NBLK    512
#define NTHR    256

typedef _Float16 half8v __attribute__((ext_vector_type(8)));
typedef _Float16 half4v __attribute__((ext_vector_type(4)));
typedef _Float16 half2v __attribute__((ext_vector_type(2)));
typedef float f32x4 __attribute__((ext_vector_type(4)));

__device__ inline f32x4 MFMA(half8v a, half8v b, f32x4 c) {
    return __builtin_amdgcn_mfma_f32_16x16x32_f16(a, b, c, 0, 0, 0);
}

struct P {
    const float* x_s; const float* x_t;
    const int* src_s; const int* dst_s; const int* src_t; const int* dst_t;
    const float* ea_s; const float* ea_t;
    const float* rel_w; const float* root_w; const float* in_w; const float* out_w;
    const float* rel_b; const float* in_b; const float* out_b;
    const float* g_ln; const float* b_ln; const float* gate_w; const float* gate_b;
    _Float16* x16; _Float16* agg16; _Float16* hb16; _Float16* qb16; _Float16* o16;
    _Float16* ea16s; _Float16* rel16; _Float16* root16; _Float16* in16; _Float16* outw16;
    int* cnt; int* cursor; int* row_start; int* srcs;
    float* out;
};

union SmemU {
    struct { float K[128][32]; float V[128][32]; float Pm[4][64]; float Pl[4][64];
             float Pacc[3][64][DHEAD + 1]; } at;                       // 58.8 KB
    struct { float rs[32][5]; float rq[32][5]; } ln;
    struct { int part[256]; } sc;
    struct { float sm[2][128]; float al[2][128]; float pl[2][128]; } po;
};

// ---------------- phase: zero cnt ----------------
__device__ void ph_zero(const P& p, int bid, int nb, int t) {
    int gid = bid * NTHR + t, gs = nb * NTHR;
    for (int i = gid; i < 2 * N_NODES; i += gs) p.cnt[i] = 0;
}

// ---------------- phase: f16 convert + dst histogram ----------------
__device__ void cvt_seg(const float* __restrict__ s, _Float16* __restrict__ d,
                        int n4, int gid, int gs) {
    for (int i = gid; i < n4; i += gs) {
        float4 v = ((const float4*)s)[i];
        half4v h;
        h[0] = (_Float16)v.x; h[1] = (_Float16)v.y;
        h[2] = (_Float16)v.z; h[3] = (_Float16)v.w;
        *(half4v*)(d + (size_t)i * 4) = h;
    }
}
__device__ void ph_cvth(const P& p, int bid, int nb, int t) {
    int gid = bid * NTHR + t, gs = nb * NTHR;
    cvt_seg(p.x_s,    p.x16,                 N_NODES * DIM / 4, gid, gs);
    cvt_seg(p.x_t,    p.x16 + N_NODES * DIM, N_NODES * DIM / 4, gid, gs);
    cvt_seg(p.rel_w,  p.rel16,  NLAYER * DIM * DIM / 4,     gid, gs);
    cvt_seg(p.root_w, p.root16, NLAYER * DIM * DIM / 4,     gid, gs);
    cvt_seg(p.in_w,   p.in16,   NLAYER * 3 * DIM * DIM / 4, gid, gs);
    cvt_seg(p.out_w,  p.outw16, NLAYER * DIM * DIM / 4,     gid, gs);
    for (int i = gid; i < 2 * NEDGE; i += gs) {
        int side = i >> 16, e = i & (NEDGE - 1);
        const int* dd = side ? p.dst_t : p.dst_s;
        atomicAdd(&p.cnt[side * N_NODES + dd[e]], 1);
    }
}

// ---------------- phase: exclusive scan (blocks 0,1) ----------------
__device__ void ph_scan(const P& p, int bid, int t, SmemU& sm) {
    if (bid >= 2) return;
    int side = bid;
    int local[16];
    int s = 0;
    #pragma unroll
    for (int j = 0; j < 16; ++j) { local[j] = p.cnt[side * N_NODES + t * 16 + j]; s += local[j]; }
    sm.sc.part[t] = s;
    __syncthreads();
    for (int off = 1; off < 256; off <<= 1) {
        int v = (t >= off) ? sm.sc.part[t - off] : 0;
        __syncthreads();
        sm.sc.part[t] += v;
        __syncthreads();
    }
    int run = (t == 0) ? 0 : sm.sc.part[t - 1];
    #pragma unroll
    for (int j = 0; j < 16; ++j) {
        int idx = t * 16 + j;
        p.row_start[side * (N_NODES + 1) + idx] = run;
        p.cursor[side * N_NODES + idx] = run;
        run += local[j];
    }
    if (t == 255) p.row_start[side * (N_NODES + 1) + N_NODES] = run;
}

// ---------------- phase: reorder + gather (fused) ----------------
// 16 threads per edge: compute sorted pos via atomic, write srcs + f16 edge row.
__device__ void ph_rg(const P& p, int bid, int nb, int t) {
    int g16 = t >> 4, sub = t & 15, lane = t & 63;
    for (int ef = bid * 16 + g16; ef < 2 * NEDGE; ef += nb * 16) {
        int side = ef >> 16, e = ef & (NEDGE - 1);
        const int* dd = side ? p.dst_t : p.dst_s;
        const int* ss = side ? p.src_t : p.src_s;
        const float* ea = side ? p.ea_t : p.ea_s;
        int pos = 0;
        if (sub == 0) pos = atomicAdd(&p.cursor[side * N_NODES + dd[e]], 1);
        pos = __shfl(pos, lane & ~15);     // broadcast within 16-lane group
        if (sub == 0) p.srcs[side * NEDGE + pos] = ss[e];
        const float* sp = ea + (size_t)e * DIM + sub * 8;
        float4 v0 = *(const float4*)(sp);
        float4 v1 = *(const float4*)(sp + 4);
        half8v h;
        h[0] = (_Float16)v0.x; h[1] = (_Float16)v0.y; h[2] = (_Float16)v0.z; h[3] = (_Float16)v0.w;
        h[4] = (_Float16)v1.x; h[5] = (_Float16)v1.y; h[6] = (_Float16)v1.z; h[7] = (_Float16)v1.w;
        *(half8v*)(p.ea16s + (size_t)(side * NEDGE + pos) * DIM + sub * 8) = h;
    }
}

// ---------------- phase: CSR mean aggregate (1 wave per node, 2-way unroll) ----
__device__ void ph_agg(const P& p, int bid, int nb, int t) {
    int wid = t >> 6, lane = t & 63;
    int wg = bid * 4 + wid, nw = nb * 4;
    for (int node = wg; node < NROWS; node += nw) {
        int side = node >> 12, n = node & (N_NODES - 1);
        const int* sp = p.srcs + side * NEDGE;
        const _Float16* ep = p.ea16s + (size_t)side * NEDGE * DIM + lane * 2;
        const _Float16* xp = p.x16 + (size_t)side * N_NODES * DIM + lane * 2;
        int rs = p.row_start[side * (N_NODES + 1) + n];
        int re = p.row_start[side * (N_NODES + 1) + n + 1];
        float ax = 0.f, ay = 0.f;
        int i = rs;
        for (; i + 2 <= re; i += 2) {
            int s0 = sp[i], s1 = sp[i + 1];
            half2v w0 = *(const half2v*)(ep + (size_t)i * DIM);
            half2v w1 = *(const half2v*)(ep + (size_t)(i + 1) * DIM);
            half2v x0 = *(const half2v*)(xp + (size_t)s0 * DIM);
            half2v x1 = *(const half2v*)(xp + (size_t)s1 * DIM);
            ax += (float)w0[0] * (float)x0[0] + (float)w1[0] * (float)x1[0];
            ay += (float)w0[1] * (float)x0[1] + (float)w1[1] * (float)x1[1];
        }
        if (i < re) {
            int s0 = sp[i];
            half2v w0 = *(const half2v*)(ep + (size_t)i * DIM);
            half2v x0 = *(const half2v*)(xp + (size_t)s0 * DIM);
            ax += (float)w0[0] * (float)x0[0];
            ay += (float)w0[1] * (float)x0[1];
        }
        float sc = 1.0f / (float)max(re - rs, 1);
        half2v o; o[0] = (_Float16)(ax * sc); o[1] = (_Float16)(ay * sc);
        *(half2v*)(p.agg16 + (size_t)node * DIM + lane * 2) = o;
    }
}

// ---------------- phase: conv GEMM (dual source), 512 tasks of 32x64 ----------
__device__ void ph_conv(const P& p, int L, int bid, int nb, int t) {
    const _Float16* wroot = p.root16 + (size_t)L * DIM * DIM;
    const _Float16* wrel  = p.rel16  + (size_t)L * DIM * DIM;
    const float* brel = p.rel_b + (size_t)L * DIM;
    int wave = t >> 6, lane = t & 63;
    int lr = lane & 15, lk = (lane >> 4) * 8;
    for (int task = bid; task < 512; task += nb) {
        int row0 = (task >> 1) * 32;
        int colb = (task & 1) * 64 + wave * 16;
        f32x4 zero = {0.f, 0.f, 0.f, 0.f};
        f32x4 acc[2] = {zero, zero};
        const _Float16* A1  = p.x16   + (size_t)(row0 + lr) * DIM + lk;
        const _Float16* A1b = p.x16   + (size_t)(row0 + 16 + lr) * DIM + lk;
        const _Float16* A2  = p.agg16 + (size_t)(row0 + lr) * DIM + lk;
        const _Float16* A2b = p.agg16 + (size_t)(row0 + 16 + lr) * DIM + lk;
        const _Float16* B1  = wroot + (size_t)(colb + lr) * DIM + lk;
        const _Float16* B2  = wrel  + (size_t)(colb + lr) * DIM + lk;
        #pragma unroll
        for (int k0 = 0; k0 < DIM; k0 += 32) {
            half8v b1 = *(const half8v*)(B1 + k0);
            acc[0] = MFMA(*(const half8v*)(A1 + k0),  b1, acc[0]);
            acc[1] = MFMA(*(const half8v*)(A1b + k0), b1, acc[1]);
            half8v b2 = *(const half8v*)(B2 + k0);
            acc[0] = MFMA(*(const half8v*)(A2 + k0),  b2, acc[0]);
            acc[1] = MFMA(*(const half8v*)(A2b + k0), b2, acc[1]);
        }
        int g4 = (lane >> 4) * 4;
        int col = colb + lr;
        float bv = brel[col];
        #pragma unroll
        for (int fr = 0; fr < 2; ++fr)
            #pragma unroll
            for (int j = 0; j < 4; ++j)
                p.hb16[(size_t)(row0 + fr * 16 + g4 + j) * DIM + col] = (_Float16)(acc[fr][j] + bv);
    }
}

// ---------------- phase: qkv GEMM, 1536 tasks of 32x64 (Ncols=384) ----------
__device__ void ph_qkv(const P& p, int L, int bid, int nb, int t) {
    const _Float16* win = p.in16 + (size_t)L * 3 * DIM * DIM;
    const float* bin = p.in_b + (size_t)L * 3 * DIM;
    int wave = t >> 6, lane = t & 63;
    int lr = lane & 15, lk = (lane >> 4) * 8;
    for (int task = bid; task < 1536; task += nb) {
        int row0 = (task & 255) * 32;
        int colb = (task >> 8) * 64 + wave * 16;
        f32x4 zero = {0.f, 0.f, 0.f, 0.f};
        f32x4 acc[2] = {zero, zero};
        const _Float16* A0 = p.hb16 + (size_t)(row0 + lr) * DIM + lk;
        const _Float16* A1 = p.hb16 + (size_t)(row0 + 16 + lr) * DIM + lk;
        const _Float16* B0 = win + (size_t)(colb + lr) * DIM + lk;
        #pragma unroll
        for (int k0 = 0; k0 < DIM; k0 += 32) {
            half8v b = *(const half8v*)(B0 + k0);
            acc[0] = MFMA(*(const half8v*)(A0 + k0), b, acc[0]);
            acc[1] = MFMA(*(const half8v*)(A1 + k0), b, acc[1]);
        }
        int g4 = (lane >> 4) * 4;
        int col = colb + lr;
        float bv = bin[col];
        #pragma unroll
        for (int fr = 0; fr < 2; ++fr)
            #pragma unroll
            for (int j = 0; j < 4; ++j)
                p.qb16[(size_t)(row0 + fr * 16 + g4 + j) * (3 * DIM) + col] = (_Float16)(acc[fr][j] + bv);
    }
}

// ---------------- phase: attention, 512 tasks (g, h, dir, qhalf) ----------
__device__ void ph_attn(const P& p, int bid, int nb, int t, SmemU& sm) {
    for (int task = bid; task < 512; task += nb) {
        int g = task >> 4, h = (task >> 2) & 3, dir = (task >> 1) & 1, qh = task & 1;
        int qoff  = dir ? N_NODES : 0;
        int kvoff = dir ? 0 : N_NODES;
        {   // stage K/V (f32 LDS): r = row, c = dim-half
            int r = t >> 1, c = (t & 1) * 16;
            const _Float16* base = p.qb16 + (size_t)(kvoff + g * 128 + r) * (3 * DIM) + DIM + h * DHEAD + c;
            half8v k0 = *(const half8v*)(base);
            half8v k1 = *(const half8v*)(base + 8);
            half8v v0 = *(const half8v*)(base + DIM);
            half8v v1 = *(const half8v*)(base + DIM + 8);
            #pragma unroll
            for (int j = 0; j < 8; ++j) {
                sm.at.K[r][c + j] = (float)k0[j]; sm.at.K[r][c + 8 + j] = (float)k1[j];
                sm.at.V[r][c + j] = (float)v0[j]; sm.at.V[r][c + 8 + j] = (float)v1[j];
            }
        }
        int row = t & 63, qt = t >> 6;
        const float scale = 0.17677669529663687f;  // 1/sqrt(32)
        float q[DHEAD];
        const _Float16* qp = p.qb16 + (size_t)(qoff + g * 128 + qh * 64 + row) * (3 * DIM) + h * DHEAD;
        #pragma unroll
        for (int j = 0; j < DHEAD; j += 8) {
            half8v qv = *(const half8v*)(qp + j);
            #pragma unroll
            for (int u = 0; u < 8; ++u) q[j + u] = (float)qv[u] * scale;
        }
        __syncthreads();
        int kn0 = qt * 32;
        float s[32];
        float m = -INFINITY;
        #pragma unroll
        for (int i = 0; i < 32; ++i) {
            float d = 0.f;
            #pragma unroll
            for (int j = 0; j < DHEAD; j += 4) {
                float4 kv = *(const float4*)&sm.at.K[kn0 + i][j];
                d += q[j] * kv.x + q[j + 1] * kv.y + q[j + 2] * kv.z + q[j + 3] * kv.w;
            }
            s[i] = d;
            m = fmaxf(m, d);
        }
        sm.at.Pm[qt][row] = m;
        __syncthreads();
        float gm = fmaxf(fmaxf(sm.at.Pm[0][row], sm.at.Pm[1][row]),
                         fmaxf(sm.at.Pm[2][row], sm.at.Pm[3][row]));
        float l = 0.f;
        float acc[DHEAD];
        #pragma unroll
        for (int j = 0; j < DHEAD; ++j) acc[j] = 0.f;
        #pragma unroll
        for (int i = 0; i < 32; ++i) {
            float pr = __expf(s[i] - gm);
            l += pr;
            #pragma unroll
            for (int j = 0; j < DHEAD; j += 4) {
                float4 vv = *(const float4*)&sm.at.V[kn0 + i][j];
                acc[j]     += pr * vv.x;
                acc[j + 1] += pr * vv.y;
                acc[j + 2] += pr * vv.z;
                acc[j + 3] += pr * vv.w;
            }
        }
        if (qt > 0) {
            sm.at.Pl[qt][row] = l;
            #pragma unroll
            for (int j = 0; j < DHEAD; ++j) sm.at.Pacc[qt - 1][row][j] = acc[j];
        }
        __syncthreads();
        if (qt == 0) {
            float lt = l + sm.at.Pl[1][row] + sm.at.Pl[2][row] + sm.at.Pl[3][row];
            float inv = 1.0f / lt;
            _Float16* op = p.o16 + (size_t)(qoff + g * 128 + qh * 64 + row) * DIM + h * DHEAD;
            #pragma unroll
            for (int j = 0; j < DHEAD; ++j) {
                float v = acc[j] + sm.at.Pacc[0][row][j] + sm.at.Pacc[1][row][j] + sm.at.Pacc[2][row][j];
                op[j] = (_Float16)(v * inv);
            }
        }
        __syncthreads();
    }
}

// ---------------- phase: out-proj GEMM + LayerNorm, 256 tasks of 32x128 ------
__device__ void ph_ln(const P& p, int L, int bid, int nb, int t, SmemU& sm) {
    const _Float16* W = p.outw16 + (size_t)L * DIM * DIM;
    const float* bias = p.out_b + (size_t)L * DIM;
    const float* gamma = p.g_ln + (size_t)L * DIM;
    const float* beta = p.b_ln + (size_t)L * DIM;
    int wave = t >> 6, lane = t & 63;
    int lr = lane & 15, lk = (lane >> 4) * 8;
    int col0 = wave * 32;
    for (int task = bid; task < 256; task += nb) {
        int row0 = task * 32;
        f32x4 zero = {0.f, 0.f, 0.f, 0.f};
        f32x4 acc[2][2] = {{zero, zero}, {zero, zero}};
        const _Float16* Ap0 = p.o16 + (size_t)(row0 + lr) * DIM + lk;
        const _Float16* Ap1 = p.o16 + (size_t)(row0 + 16 + lr) * DIM + lk;
        const _Float16* Wp0 = W + (size_t)(col0 + lr) * DIM + lk;
        const _Float16* Wp1 = W + (size_t)(col0 + 16 + lr) * DIM + lk;
        #pragma unroll
        for (int k0 = 0; k0 < DIM; k0 += 32) {
            half8v a0 = *(const half8v*)(Ap0 + k0);
            half8v a1 = *(const half8v*)(Ap1 + k0);
            half8v b0 = *(const half8v*)(Wp0 + k0);
            half8v b1 = *(const half8v*)(Wp1 + k0);
            acc[0][0] = MFMA(a0, b0, acc[0][0]);
            acc[0][1] = MFMA(a0, b1, acc[0][1]);
            acc[1][0] = MFMA(a1, b0, acc[1][0]);
            acc[1][1] = MFMA(a1, b1, acc[1][1]);
        }
        int g = lane >> 4;
        float v[2][2][4];
        #pragma unroll
        for (int fc = 0; fc < 2; ++fc) {
            float bv = bias[col0 + fc * 16 + lr];
            #pragma unroll
            for (int fr = 0; fr < 2; ++fr)
                #pragma unroll
                for (int j = 0; j < 4; ++j)
                    v[fr][fc][j] = acc[fr][fc][j] + bv;
        }
        float ss[2][4], qq[2][4];
        #pragma unroll
        for (int fr = 0; fr < 2; ++fr)
            #pragma unroll
            for (int j = 0; j < 4; ++j) {
                float a = v[fr][0][j] + v[fr][1][j];
                float b = v[fr][0][j] * v[fr][0][j] + v[fr][1][j] * v[fr][1][j];
                #pragma unroll
                for (int mk = 1; mk < 16; mk <<= 1) {
                    a += __shfl_xor(a, mk);
                    b += __shfl_xor(b, mk);
                }
                ss[fr][j] = a; qq[fr][j] = b;
            }
        if (lr == 0) {
            #pragma unroll
            for (int fr = 0; fr < 2; ++fr)
                #pragma unroll
                for (int j = 0; j < 4; ++j) {
                    sm.ln.rs[fr * 16 + g * 4 + j][wave] = ss[fr][j];
                    sm.ln.rq[fr * 16 + g * 4 + j][wave] = qq[fr][j];
                }
        }
        __syncthreads();
        #pragma unroll
        for (int fr = 0; fr < 2; ++fr)
            #pragma unroll
            for (int j = 0; j < 4; ++j) {
                int r = fr * 16 + g * 4 + j;
                float S = sm.ln.rs[r][0] + sm.ln.rs[r][1] + sm.ln.rs[r][2] + sm.ln.rs[r][3];
                float Q = sm.ln.rq[r][0] + sm.ln.rq[r][1] + sm.ln.rq[r][2] + sm.ln.rq[r][3];
                float mu = S * (1.0f / 128.0f);
                float inv = rsqrtf(Q * (1.0f / 128.0f) - mu * mu + 1e-5f);
                #pragma unroll
                for (int fc = 0; fc < 2; ++fc) {
                    int col = col0 + fc * 16 + lr;
                    float o = (v[fr][fc][j] - mu) * inv * gamma[col] + beta[col];
                    p.x16[(size_t)(row0 + r) * DIM + col] = (_Float16)o;
                }
            }
        __syncthreads();
    }
}

// ---------------- phase: pool + cosine, 32 tasks ----------------
__device__ void ph_pool(const P& p, int bid, int nb, int t, SmemU& sm) {
    for (int task = bid; task < BGRAPH; task += nb) {
        int g = task;
        int side = t >> 7, r = t & 127;
        const _Float16* xr = p.x16 + (size_t)(side * N_NODES + g * 128 + r) * DIM;
        float dot = p.gate_b[0];
        #pragma unroll
        for (int d = 0; d < DIM; d += 8) {
            half8v xv = *(const half8v*)(xr + d);
            #pragma unroll
            for (int u = 0; u < 8; ++u) dot += (float)xv[u] * p.gate_w[d + u];
        }
        float gate = 1.0f / (1.0f + __expf(-dot));
        sm.po.sm[side][r] = gate; __syncthreads();
        for (int sN = 64; sN > 0; sN >>= 1) {
            if (r < sN) sm.po.sm[side][r] = fmaxf(sm.po.sm[side][r], sm.po.sm[side][r + sN]);
            __syncthreads();
        }
        float m = sm.po.sm[side][0]; __syncthreads();
        float e = __expf(gate - m);
        sm.po.sm[side][r] = e; __syncthreads();
        for (int sN = 64; sN > 0; sN >>= 1) {
            if (r < sN) sm.po.sm[side][r] += sm.po.sm[side][r + sN];
            __syncthreads();
        }
        sm.po.al[side][r] = e / sm.po.sm[side][0];
        __syncthreads();
        int d = t & 127;
        float acc = 0.0f;
        const _Float16* xg = p.x16 + (size_t)(side * N_NODES + g * 128) * DIM;
        for (int n = 0; n < 128; ++n) acc += sm.po.al[side][n] * (float)xg[(size_t)n * DIM + d];
        sm.po.pl[side][d] = acc;
        __syncthreads();
        if (t < 64) {
            float a0 = sm.po.pl[0][t], a1 = sm.po.pl[0][64 + t];
            float b0 = sm.po.pl[1][t], b1 = sm.po.pl[1][64 + t];
            float saa = a0 * a0 + a1 * a1;
            float sbb = b0 * b0 + b1 * b1;
            float sab = a0 * b0 + a1 * b1;
            #pragma unroll
            for (int off = 32; off; off >>= 1) {
                saa += __shfl_down(saa, off);
                sbb += __shfl_down(sbb, off);
                sab += __shfl_down(sab, off);
            }
            if (t == 0) {
                float na = fmaxf(sqrtf(saa), 1e-12f);
                float nb2 = fmaxf(sqrtf(sbb), 1e-12f);
                p.out[g] = sab / (na * nb2);
            }
        }
        __syncthreads();
    }
}

// ---------------- cooperative mega-kernel ----------------
__global__ __launch_bounds__(NTHR, 2) void mega(P p) {
    cg::grid_group gg = cg::this_grid();
    int bid = blockIdx.x, nb = gridDim.x, t = threadIdx.x;
    __shared__ SmemU sm;
    ph_zero(p, bid, nb, t);       gg.sync();
    ph_cvth(p, bid, nb, t);       gg.sync();
    ph_scan(p, bid, t, sm);       gg.sync();
    ph_rg(p, bid, nb, t);         gg.sync();
    for (int L = 0; L < NLAYER; ++L) {
        ph_agg(p, bid, nb, t);        gg.sync();
        ph_conv(p, L, bid, nb, t);    gg.sync();
        ph_qkv(p, L, bid, nb, t);     gg.sync();
        ph_attn(p, bid, nb, t, sm);   gg.sync();
        ph_ln(p, L, bid, nb, t, sm);  gg.sync();
    }
    ph_pool(p, bid, nb, t, sm);
}

// ---------------- fallback wrappers (regular launches) ----------------
__global__ __launch_bounds__(NTHR) void k_zero(P p)        { ph_zero(p, blockIdx.x, gridDim.x, threadIdx.x); }
__global__ __launch_bounds__(NTHR) void k_cvth(P p)        { ph_cvth(p, blockIdx.x, gridDim.x, threadIdx.x); }
__global__ __launch_bounds__(NTHR) void k_scan(P p)        { __shared__ SmemU sm; ph_scan(p, blockIdx.x, threadIdx.x, sm); }
__global__ __launch_bounds__(NTHR) void k_rg(P p)          { ph_rg(p, blockIdx.x, gridDim.x, threadIdx.x); }
__global__ __launch_bounds__(NTHR) void k_agg(P p)         { ph_agg(p, blockIdx.x, gridDim.x, threadIdx.x); }
__global__ __launch_bounds__(NTHR) void k_conv(P p, int L) { ph_conv(p, L, blockIdx.x, gridDim.x, threadIdx.x); }
__global__ __launch_bounds__(NTHR) void k_qkv(P p, int L)  { ph_qkv(p, L, blockIdx.x, gridDim.x, threadIdx.x); }
__global__ __launch_bounds__(NTHR) void k_attn(P p)        { __shared__ SmemU sm; ph_attn(p, blockIdx.x, gridDim.x, threadIdx.x, sm); }
__global__ __launch_bounds__(NTHR) void k_ln(P p, int L)   { __shared__ SmemU sm; ph_ln(p, L, blockIdx.x, gridDim.x, threadIdx.x, sm); }
__global__ __launch_bounds__(NTHR) void k_pool(P p)        { __shared__ SmemU sm; ph_pool(p, blockIdx.x, gridDim.x, threadIdx.x, sm); }

extern "C" void kernel_launch(void* const* d_in, const int* in_sizes, int n_in,
                              void* d_out, int out_size, void* d_ws, size_t ws_size,
                              hipStream_t stream)
{
    const size_t RD = (size_t)NROWS * DIM;
    _Float16* h16p = (_Float16*)d_ws;
    _Float16* x16    = h16p; h16p += RD;
    _Float16* agg16  = h16p; h16p += RD;
    _Float16* hb16   = h16p; h16p += RD;
    _Float16* qb16   = h16p; h16p += RD * 3;
    _Float16* o16    = h16p; h16p += RD;
    _Float16* ea16s  = h16p; h16p += (size_t)2 * NEDGE * DIM;
    _Float16* rel16  = h16p; h16p += (size_t)NLAYER * DIM * DIM;
    _Float16* root16 = h16p; h16p += (size_t)NLAYER * DIM * DIM;
    _Float16* in16   = h16p; h16p += (size_t)NLAYER * 3 * DIM * DIM;
    _Float16* outw16 = h16p; h16p += (size_t)NLAYER * DIM * DIM;
    int* iws = (int*)h16p;
    int* cnt       = iws; iws += 2 * N_NODES;
    int* cursor    = iws; iws += 2 * N_NODES;
    int* row_start = iws; iws += 2 * (N_NODES + 1);
    int* srcs      = iws; iws += 2 * NEDGE;

    P p;
    p.x_s    = (const float*)d_in[0];
    p.x_t    = (const float*)d_in[1];
    p.src_s  = (const int*)d_in[2];
    p.dst_s  = (const int*)d_in[2] + NEDGE;
    p.ea_s   = (const float*)d_in[3];
    p.src_t  = (const int*)d_in[4];
    p.dst_t  = (const int*)d_in[4] + NEDGE;
    p.ea_t   = (const float*)d_in[5];
    p.rel_w  = (const float*)d_in[8];
    p.rel_b  = (const float*)d_in[9];
    p.root_w = (const float*)d_in[10];
    p.in_w   = (const float*)d_in[11];
    p.in_b   = (const float*)d_in[12];
    p.out_w  = (const float*)d_in[13];
    p.out_b  = (const float*)d_in[14];
    p.g_ln   = (const float*)d_in[15];
    p.b_ln   = (const float*)d_in[16];
    p.gate_w = (const float*)d_in[17];
    p.gate_b = (const float*)d_in[18];
    p.x16 = x16; p.agg16 = agg16; p.hb16 = hb16; p.qb16 = qb16; p.o16 = o16;
    p.ea16s = ea16s; p.rel16 = rel16; p.root16 = root16; p.in16 = in16; p.outw16 = outw16;
    p.cnt = cnt; p.cursor = cursor; p.row_start = row_start; p.srcs = srcs;
    p.out = (float*)d_out;

    void* args[] = { (void*)&p };
    hipError_t err = hipLaunchCooperativeKernel((const void*)mega, dim3(NBLK), dim3(NTHR),
                                                args, 0, stream);
    if (err != hipSuccess) {
        // fallback: same phases as regular dispatches
        k_zero<<<32, NTHR, 0, stream>>>(p);
        k_cvth<<<512, NTHR, 0, stream>>>(p);
        k_scan<<<2, NTHR, 0, stream>>>(p);
        k_rg<<<512, NTHR, 0, stream>>>(p);
        for (int L = 0; L < NLAYER; ++L) {
            k_agg<<<2048, NTHR, 0, stream>>>(p);
            k_conv<<<512, NTHR, 0, stream>>>(p, L);
            k_qkv<<<512, NTHR, 0, stream>>>(p, L);
            k_attn<<<512, NTHR, 0, stream>>>(p);
            k_ln<<<256, NTHR, 0, stream>>>(p, L);
        }
        k_pool<<<32, NTHR, 0, stream>>>(p);
    }
}

// Round 8
// 275.447 us; speedup vs baseline: 6.2044x; 6.2044x over previous
//
#include <hip/hip_runtime.h>
#include <math.h>

#define N_NODES 4096
#define NROWS   8192      // both sides stacked
#define BGRAPH  32
#define NEDGE   65536
#define DIM     128
#define NLAYER  4
#define NHEAD   4
#define DHEAD   32
#define QDIM    384       // 3*DIM

typedef _Float16 half8v __attribute__((ext_vector_type(8)));
typedef _Float16 half4v __attribute__((ext_vector_type(4)));
typedef _Float16 half2v __attribute__((ext_vector_type(2)));
typedef float f32x4 __attribute__((ext_vector_type(4)));

__device__ inline f32x4 MFMA(half8v a, half8v b, f32x4 c) {
    return __builtin_amdgcn_mfma_f32_16x16x32_f16(a, b, c, 0, 0, 0);
}

// ---------------- setup: f16 convert (x, out_w) + dst histogram ----------------
__device__ inline void cvt4(const float* __restrict__ s, _Float16* __restrict__ d, int i) {
    float4 v = ((const float4*)s)[i];
    half4v h;
    h[0] = (_Float16)v.x; h[1] = (_Float16)v.y;
    h[2] = (_Float16)v.z; h[3] = (_Float16)v.w;
    *(half4v*)(d + (size_t)i * 4) = h;
}

__global__ __launch_bounds__(256) void cvth_kernel(
    const float* __restrict__ x_s, const float* __restrict__ x_t,
    const float* __restrict__ out_w,
    const int* __restrict__ dst_s, const int* __restrict__ dst_t,
    _Float16* __restrict__ x16, _Float16* __restrict__ outw16,
    int* __restrict__ cnt)
{
    int gid = blockIdx.x * 256 + threadIdx.x, gs = gridDim.x * 256;
    const int nx = N_NODES * DIM / 4;
    const int nw = NLAYER * DIM * DIM / 4;
    for (int i = gid; i < nx; i += gs) cvt4(x_s, x16, i);
    for (int i = gid; i < nx; i += gs) cvt4(x_t, x16 + N_NODES * DIM, i);
    for (int i = gid; i < nw; i += gs) cvt4(out_w, outw16, i);
    for (int i = gid; i < 2 * NEDGE; i += gs) {
        int side = i >> 16, e = i & (NEDGE - 1);
        const int* dd = side ? dst_t : dst_s;
        atomicAdd(&cnt[side * N_NODES + dd[e]], 1);
    }
}

// ---------------- setup: exclusive scan (2 blocks) ----------------
__global__ __launch_bounds__(256) void scan_kernel(
    const int* __restrict__ cnt, int* __restrict__ row_start, int* __restrict__ cursor)
{
    int side = blockIdx.x;
    int t = threadIdx.x;
    __shared__ int part[256];
    int local[16];
    int s = 0;
    #pragma unroll
    for (int j = 0; j < 16; ++j) { local[j] = cnt[side * N_NODES + t * 16 + j]; s += local[j]; }
    part[t] = s;
    __syncthreads();
    for (int off = 1; off < 256; off <<= 1) {
        int v = (t >= off) ? part[t - off] : 0;
        __syncthreads();
        part[t] += v;
        __syncthreads();
    }
    int run = (t == 0) ? 0 : part[t - 1];
    #pragma unroll
    for (int j = 0; j < 16; ++j) {
        int idx = t * 16 + j;
        row_start[side * (N_NODES + 1) + idx] = run;
        cursor[side * N_NODES + idx] = run;
        run += local[j];
    }
    if (t == 255) row_start[side * (N_NODES + 1) + N_NODES] = run;
}

// ---------------- setup: fused reorder + gather (f16 sorted edge rows) --------
// 16 threads per edge; atomic cursor gives sorted pos, shfl-broadcast within group.
__global__ __launch_bounds__(256) void rg_kernel(
    const int* __restrict__ src_s, const int* __restrict__ dst_s,
    const int* __restrict__ src_t, const int* __restrict__ dst_t,
    const float* __restrict__ ea_s, const float* __restrict__ ea_t,
    int* __restrict__ cursor, int* __restrict__ srcs, _Float16* __restrict__ ea16s)
{
    int t = threadIdx.x;
    int g16 = t >> 4, sub = t & 15, lane = t & 63;
    int ef = blockIdx.x * 16 + g16;                  // [0, 2*NEDGE)
    int side = ef >> 16, e = ef & (NEDGE - 1);
    const int* dd = side ? dst_t : dst_s;
    const int* ss = side ? src_t : src_s;
    const float* ea = side ? ea_t : ea_s;
    int pos = 0;
    if (sub == 0) pos = atomicAdd(&cursor[side * N_NODES + dd[e]], 1);
    pos = __shfl(pos, lane & ~15);                   // broadcast within 16-group
    if (sub == 0) srcs[side * NEDGE + pos] = ss[e];
    const float* sp = ea + (size_t)e * DIM + sub * 8;
    float4 v0 = *(const float4*)(sp);
    float4 v1 = *(const float4*)(sp + 4);
    half8v h;
    h[0] = (_Float16)v0.x; h[1] = (_Float16)v0.y; h[2] = (_Float16)v0.z; h[3] = (_Float16)v0.w;
    h[4] = (_Float16)v1.x; h[5] = (_Float16)v1.y; h[6] = (_Float16)v1.z; h[7] = (_Float16)v1.w;
    *(half8v*)(ea16s + (size_t)(side * NEDGE + pos) * DIM + sub * 8) = h;
}

// ---------------- setup: fold conv into qkv weights ----------------
// wq16[L][0] = Win@Wroot, wq16[L][1] = Win@Wrel  (both [384][128] f16)
// beff[L]    = Win@brel + bin                    ([384] f32)
__global__ __launch_bounds__(256) void wprod_kernel(
    const float* __restrict__ in_w, const float* __restrict__ root_w,
    const float* __restrict__ rel_w, const float* __restrict__ rel_b,
    const float* __restrict__ in_b,
    _Float16* __restrict__ wq16, float* __restrict__ beff)
{
    int gid = blockIdx.x * 256 + threadIdx.x;
    const int MT = NLAYER * 2 * QDIM * DIM;
    if (gid < MT) {
        int L = gid / (2 * QDIM * DIM);
        int r = gid % (2 * QDIM * DIM);
        int m = r / (QDIM * DIM);
        int r2 = r % (QDIM * DIM);
        int i = r2 / DIM, k = r2 % DIM;
        const float* Win = in_w + (size_t)L * QDIM * DIM;
        const float* B = (m ? rel_w : root_w) + (size_t)L * DIM * DIM;
        float s = 0.f;
        #pragma unroll 4
        for (int j = 0; j < DIM; ++j) s += Win[i * DIM + j] * B[j * DIM + k];
        wq16[gid] = (_Float16)s;
    } else {
        int r = gid - MT;                         // [0, NLAYER*QDIM)
        if (r >= NLAYER * QDIM) return;
        int L = r / QDIM, i = r % QDIM;
        const float* Win = in_w + (size_t)L * QDIM * DIM;
        const float* br = rel_b + (size_t)L * DIM;
        float s = in_b[(size_t)L * QDIM + i];
        #pragma unroll 4
        for (int j = 0; j < DIM; ++j) s += Win[i * DIM + j] * br[j];
        beff[r] = s;
    }
}

// ---------------- per-layer: CSR mean aggregate (1 wave per node) ----------
__global__ __launch_bounds__(64) void agg_kernel(
    const int* __restrict__ srcs, const _Float16* __restrict__ ea16s,
    const int* __restrict__ row_start,
    const _Float16* __restrict__ x16, _Float16* __restrict__ agg16)
{
    int n = blockIdx.x, side = blockIdx.y;
    int lane = threadIdx.x;
    const int* sp = srcs + side * NEDGE;
    const _Float16* ep = ea16s + (size_t)side * NEDGE * DIM + lane * 2;
    const _Float16* xp = x16 + (size_t)side * N_NODES * DIM + lane * 2;
    int rs = row_start[side * (N_NODES + 1) + n];
    int re = row_start[side * (N_NODES + 1) + n + 1];
    float ax = 0.f, ay = 0.f;
    int i = rs;
    for (; i + 2 <= re; i += 2) {
        int s0 = sp[i], s1 = sp[i + 1];
        half2v w0 = *(const half2v*)(ep + (size_t)i * DIM);
        half2v w1 = *(const half2v*)(ep + (size_t)(i + 1) * DIM);
        half2v x0 = *(const half2v*)(xp + (size_t)s0 * DIM);
        half2v x1 = *(const half2v*)(xp + (size_t)s1 * DIM);
        ax += (float)w0[0] * (float)x0[0] + (float)w1[0] * (float)x1[0];
        ay += (float)w0[1] * (float)x0[1] + (float)w1[1] * (float)x1[1];
    }
    if (i < re) {
        int s0 = sp[i];
        half2v w0 = *(const half2v*)(ep + (size_t)i * DIM);
        half2v x0 = *(const half2v*)(xp + (size_t)s0 * DIM);
        ax += (float)w0[0] * (float)x0[0];
        ay += (float)w0[1] * (float)x0[1];
    }
    float sc = 1.0f / (float)max(re - rs, 1);
    half2v o; o[0] = (_Float16)(ax * sc); o[1] = (_Float16)(ay * sc);
    *(half2v*)(agg16 + (size_t)(side * N_NODES + n) * DIM + lane * 2) = o;
}

// ---------------- per-layer: fused conv+qkv dual-source MFMA GEMM ----------
// qkv = x16 @ Wqroot^T + agg16 @ Wqrel^T + beff    (64x64 tile, 4 waves 2x2)
__global__ __launch_bounds__(256) void qkv2_mfma(
    const _Float16* __restrict__ x16, const _Float16* __restrict__ agg16,
    const _Float16* __restrict__ wq,     // [2][384][128] this layer
    const float* __restrict__ beff,      // [384]
    _Float16* __restrict__ qb16)
{
    int tid = threadIdx.x;
    int wave = tid >> 6, lane = tid & 63;
    int wm = wave >> 1, wn = wave & 1;
    int row0 = blockIdx.x * 64 + wm * 32;
    int col0 = blockIdx.y * 64 + wn * 32;
    int lr = lane & 15;
    int lk = (lane >> 4) * 8;
    f32x4 zero = {0.f, 0.f, 0.f, 0.f};
    f32x4 acc[2][2] = {{zero, zero}, {zero, zero}};
    #pragma unroll
    for (int s = 0; s < 2; ++s) {
        const _Float16* A = s ? agg16 : x16;
        const _Float16* W = wq + (size_t)s * QDIM * DIM;
        const _Float16* Ap0 = A + (size_t)(row0 + lr) * DIM + lk;
        const _Float16* Ap1 = A + (size_t)(row0 + 16 + lr) * DIM + lk;
        const _Float16* Wp0 = W + (size_t)(col0 + lr) * DIM + lk;
        const _Float16* Wp1 = W + (size_t)(col0 + 16 + lr) * DIM + lk;
        #pragma unroll
        for (int k0 = 0; k0 < DIM; k0 += 32) {
            half8v a0 = *(const half8v*)(Ap0 + k0);
            half8v a1 = *(const half8v*)(Ap1 + k0);
            half8v b0 = *(const half8v*)(Wp0 + k0);
            half8v b1 = *(const half8v*)(Wp1 + k0);
            acc[0][0] = MFMA(a0, b0, acc[0][0]);
            acc[0][1] = MFMA(a0, b1, acc[0][1]);
            acc[1][0] = MFMA(a1, b0, acc[1][0]);
            acc[1][1] = MFMA(a1, b1, acc[1][1]);
        }
    }
    int g4 = (lane >> 4) * 4;
    #pragma unroll
    for (int fc = 0; fc < 2; ++fc) {
        int col = col0 + fc * 16 + lr;
        float bv = beff[col];
        #pragma unroll
        for (int fr = 0; fr < 2; ++fr) {
            int rbase = row0 + fr * 16 + g4;
            #pragma unroll
            for (int j = 0; j < 4; ++j) {
                float v = acc[fr][fc][j] + bv;
                qb16[(size_t)(rbase + j) * QDIM + col] = (_Float16)v;
            }
        }
    }
}

// ---------------- per-layer: attention (unchanged from r6) ----------------
__global__ __launch_bounds__(512) void attn_kernel(
    const _Float16* __restrict__ qkv, _Float16* __restrict__ o16)
{
    int g = blockIdx.x, h = blockIdx.y, dir = blockIdx.z;
    int qoff  = dir ? N_NODES : 0;
    int kvoff = dir ? 0 : N_NODES;
    int t = threadIdx.x;
    int row = t & 127;
    int qt = t >> 7;
    __shared__ float Klds[128][DHEAD];
    __shared__ float Vlds[128][DHEAD];
    __shared__ float Pm[4][128];
    __shared__ float Pl[4][128];
    __shared__ float Pacc[4][128][DHEAD + 1];
    {
        int r = t >> 2, c = (t & 3) * 8;
        const _Float16* base = qkv + (size_t)(kvoff + g * 128 + r) * QDIM + DIM + h * DHEAD + c;
        half8v kv = *(const half8v*)(base);
        half8v vv = *(const half8v*)(base + DIM);
        #pragma unroll
        for (int j = 0; j < 8; ++j) {
            Klds[r][c + j] = (float)kv[j];
            Vlds[r][c + j] = (float)vv[j];
        }
    }
    const float scale = 0.17677669529663687f;
    float q[DHEAD];
    const _Float16* qp = qkv + (size_t)(qoff + g * 128 + row) * QDIM + h * DHEAD;
    #pragma unroll
    for (int j = 0; j < DHEAD; j += 8) {
        half8v qv = *(const half8v*)(qp + j);
        #pragma unroll
        for (int u = 0; u < 8; ++u) q[j + u] = (float)qv[u] * scale;
    }
    __syncthreads();
    int kn0 = qt * 32;
    float s[32];
    float m = -INFINITY;
    #pragma unroll
    for (int i = 0; i < 32; ++i) {
        float d = 0.0f;
        #pragma unroll
        for (int j = 0; j < DHEAD; j += 4) {
            float4 kv = *(const float4*)&Klds[kn0 + i][j];
            d += q[j] * kv.x + q[j+1] * kv.y + q[j+2] * kv.z + q[j+3] * kv.w;
        }
        s[i] = d;
        m = fmaxf(m, d);
    }
    Pm[qt][row] = m;
    __syncthreads();
    float gm = fmaxf(fmaxf(Pm[0][row], Pm[1][row]), fmaxf(Pm[2][row], Pm[3][row]));
    float l = 0.0f;
    float acc[DHEAD];
    #pragma unroll
    for (int j = 0; j < DHEAD; ++j) acc[j] = 0.0f;
    #pragma unroll
    for (int i = 0; i < 32; ++i) {
        float p = __expf(s[i] - gm);
        l += p;
        #pragma unroll
        for (int j = 0; j < DHEAD; j += 4) {
            float4 vv = *(const float4*)&Vlds[kn0 + i][j];
            acc[j]   += p * vv.x;
            acc[j+1] += p * vv.y;
            acc[j+2] += p * vv.z;
            acc[j+3] += p * vv.w;
        }
    }
    Pl[qt][row] = l;
    #pragma unroll
    for (int j = 0; j < DHEAD; ++j) Pacc[qt][row][j] = acc[j];
    __syncthreads();
    if (qt == 0) {
        float linv = 1.0f / (Pl[0][row] + Pl[1][row] + Pl[2][row] + Pl[3][row]);
        _Float16* op = o16 + (size_t)(qoff + g * 128 + row) * DIM + h * DHEAD;
        #pragma unroll
        for (int j = 0; j < DHEAD; ++j) {
            float v = Pacc[0][row][j] + Pacc[1][row][j] + Pacc[2][row][j] + Pacc[3][row][j];
            op[j] = (_Float16)(v * linv);
        }
    }
}

// ---------------- per-layer: out-proj GEMM + LayerNorm (unchanged) ----------
__global__ __launch_bounds__(256) void gemm_ln_mfma(
    const _Float16* __restrict__ A, const _Float16* __restrict__ W,
    const float* __restrict__ bias, const float* __restrict__ gamma,
    const float* __restrict__ beta, _Float16* __restrict__ outh)
{
    int tid = threadIdx.x;
    int wave = tid >> 6, lane = tid & 63;
    int row0 = blockIdx.x * 32;
    int col0 = wave * 32;
    int lr = lane & 15;
    int lk = (lane >> 4) * 8;
    f32x4 zero = {0.f, 0.f, 0.f, 0.f};
    f32x4 acc[2][2] = {{zero, zero}, {zero, zero}};
    const _Float16* Ap0 = A + (size_t)(row0 + lr) * DIM + lk;
    const _Float16* Ap1 = A + (size_t)(row0 + 16 + lr) * DIM + lk;
    const _Float16* Wp0 = W + (size_t)(col0 + lr) * DIM + lk;
    const _Float16* Wp1 = W + (size_t)(col0 + 16 + lr) * DIM + lk;
    #pragma unroll
    for (int k0 = 0; k0 < DIM; k0 += 32) {
        half8v a0 = *(const half8v*)(Ap0 + k0);
        half8v a1 = *(const half8v*)(Ap1 + k0);
        half8v b0 = *(const half8v*)(Wp0 + k0);
        half8v b1 = *(const half8v*)(Wp1 + k0);
        acc[0][0] = MFMA(a0, b0, acc[0][0]);
        acc[0][1] = MFMA(a0, b1, acc[0][1]);
        acc[1][0] = MFMA(a1, b0, acc[1][0]);
        acc[1][1] = MFMA(a1, b1, acc[1][1]);
    }
    int g = lane >> 4;
    float v[2][2][4];
    #pragma unroll
    for (int fc = 0; fc < 2; ++fc) {
        float bv = bias[col0 + fc * 16 + lr];
        #pragma unroll
        for (int fr = 0; fr < 2; ++fr)
            #pragma unroll
            for (int j = 0; j < 4; ++j)
                v[fr][fc][j] = acc[fr][fc][j] + bv;
    }
    __shared__ float red_s[32][5];
    __shared__ float red_q[32][5];
    float s[2][4], q[2][4];
    #pragma unroll
    for (int fr = 0; fr < 2; ++fr)
        #pragma unroll
        for (int j = 0; j < 4; ++j) {
            float ss = v[fr][0][j] + v[fr][1][j];
            float qq = v[fr][0][j] * v[fr][0][j] + v[fr][1][j] * v[fr][1][j];
            #pragma unroll
            for (int m = 1; m < 16; m <<= 1) {
                ss += __shfl_xor(ss, m);
                qq += __shfl_xor(qq, m);
            }
            s[fr][j] = ss; q[fr][j] = qq;
        }
    if (lr == 0) {
        #pragma unroll
        for (int fr = 0; fr < 2; ++fr)
            #pragma unroll
            for (int j = 0; j < 4; ++j) {
                red_s[fr * 16 + g * 4 + j][wave] = s[fr][j];
                red_q[fr * 16 + g * 4 + j][wave] = q[fr][j];
            }
    }
    __syncthreads();
    #pragma unroll
    for (int fr = 0; fr < 2; ++fr)
        #pragma unroll
        for (int j = 0; j < 4; ++j) {
            int r = fr * 16 + g * 4 + j;
            float S = red_s[r][0] + red_s[r][1] + red_s[r][2] + red_s[r][3];
            float Q = red_q[r][0] + red_q[r][1] + red_q[r][2] + red_q[r][3];
            float mu = S * (1.0f / 128.0f);
            float inv = rsqrtf(Q * (1.0f / 128.0f) - mu * mu + 1e-5f);
            #pragma unroll
            for (int fc = 0; fc < 2; ++fc) {
                int col = col0 + fc * 16 + lr;
                float o = (v[fr][fc][j] - mu) * inv * gamma[col] + beta[col];
                outh[(size_t)(row0 + r) * DIM + col] = (_Float16)o;
            }
        }
}

// ---------------- pool + cosine (unchanged) ----------------
__global__ __launch_bounds__(256) void poolcos_kernel(
    const _Float16* __restrict__ x16, const float* __restrict__ gw,
    const float* __restrict__ gb, float* __restrict__ out)
{
    int g = blockIdx.x, t = threadIdx.x;
    int side = t >> 7, r = t & 127;
    __shared__ float sm[2][128];
    __shared__ float al[2][128];
    __shared__ float pl[2][DIM];
    const _Float16* xr = x16 + (size_t)(side * N_NODES + g * 128 + r) * DIM;
    float dot = gb[0];
    #pragma unroll
    for (int d = 0; d < DIM; d += 8) {
        half8v xv = *(const half8v*)(xr + d);
        #pragma unroll
        for (int u = 0; u < 8; ++u) dot += (float)xv[u] * gw[d + u];
    }
    float gate = 1.0f / (1.0f + __expf(-dot));
    sm[side][r] = gate; __syncthreads();
    for (int sN = 64; sN > 0; sN >>= 1) {
        if (r < sN) sm[side][r] = fmaxf(sm[side][r], sm[side][r + sN]);
        __syncthreads();
    }
    float m = sm[side][0]; __syncthreads();
    float e = __expf(gate - m);
    sm[side][r] = e; __syncthreads();
    for (int sN = 64; sN > 0; sN >>= 1) {
        if (r < sN) sm[side][r] += sm[side][r + sN];
        __syncthreads();
    }
    al[side][r] = e / sm[side][0];
    __syncthreads();
    int d = t & 127;
    float acc = 0.0f;
    const _Float16* xg = x16 + (size_t)(side * N_NODES + g * 128) * DIM;
    for (int n = 0; n < 128; ++n) acc += al[side][n] * (float)xg[(size_t)n * DIM + d];
    pl[side][d] = acc;
    __syncthreads();
    if (t < 64) {
        float a0 = pl[0][t], a1 = pl[0][64 + t];
        float b0 = pl[1][t], b1 = pl[1][64 + t];
        float saa = a0 * a0 + a1 * a1;
        float sbb = b0 * b0 + b1 * b1;
        float sab = a0 * b0 + a1 * b1;
        #pragma unroll
        for (int off = 32; off; off >>= 1) {
            saa += __shfl_down(saa, off);
            sbb += __shfl_down(sbb, off);
            sab += __shfl_down(sab, off);
        }
        if (t == 0) {
            float na = fmaxf(sqrtf(saa), 1e-12f);
            float nb = fmaxf(sqrtf(sbb), 1e-12f);
            out[g] = sab / (na * nb);
        }
    }
}

extern "C" void kernel_launch(void* const* d_in, const int* in_sizes, int n_in,
                              void* d_out, int out_size, void* d_ws, size_t ws_size,
                              hipStream_t stream)
{
    const float* x_s    = (const float*)d_in[0];
    const float* x_t    = (const float*)d_in[1];
    const int*   ei_s   = (const int*)d_in[2];
    const float* ea_s   = (const float*)d_in[3];
    const int*   ei_t   = (const int*)d_in[4];
    const float* ea_t   = (const float*)d_in[5];
    const float* rel_w  = (const float*)d_in[8];
    const float* rel_b  = (const float*)d_in[9];
    const float* root_w = (const float*)d_in[10];
    const float* in_w   = (const float*)d_in[11];
    const float* in_b   = (const float*)d_in[12];
    const float* out_w  = (const float*)d_in[13];
    const float* out_b  = (const float*)d_in[14];
    const float* g_ln   = (const float*)d_in[15];
    const float* b_ln   = (const float*)d_in[16];
    const float* gate_w = (const float*)d_in[17];
    const float* gate_b = (const float*)d_in[18];
    float* out = (float*)d_out;

    const size_t RD = (size_t)NROWS * DIM;
    _Float16* h16p = (_Float16*)d_ws;
    _Float16* x16    = h16p; h16p += RD;
    _Float16* agg16  = h16p; h16p += RD;
    _Float16* qb16   = h16p; h16p += RD * 3;
    _Float16* o16    = h16p; h16p += RD;
    _Float16* ea16s  = h16p; h16p += (size_t)2 * NEDGE * DIM;
    _Float16* outw16 = h16p; h16p += (size_t)NLAYER * DIM * DIM;
    _Float16* wq16   = h16p; h16p += (size_t)NLAYER * 2 * QDIM * DIM;
    float* fws = (float*)h16p;
    float* beff = fws; fws += NLAYER * QDIM;
    int* iws = (int*)fws;
    int* cnt       = iws; iws += 2 * N_NODES;
    int* cursor    = iws; iws += 2 * N_NODES;
    int* row_start = iws; iws += 2 * (N_NODES + 1);
    int* srcs      = iws; iws += 2 * NEDGE;

    const int* src_s = ei_s, *dst_s = ei_s + NEDGE;
    const int* src_t = ei_t, *dst_t = ei_t + NEDGE;

    // setup: zero hist, convert+hist, scan, reorder+gather, weight folding
    hipMemsetAsync(cnt, 0, 2 * N_NODES * 4, stream);
    cvth_kernel<<<512, 256, 0, stream>>>(x_s, x_t, out_w, dst_s, dst_t,
                                         x16, outw16, cnt);
    scan_kernel<<<2, 256, 0, stream>>>(cnt, row_start, cursor);
    rg_kernel<<<2 * NEDGE / 16, 256, 0, stream>>>(src_s, dst_s, src_t, dst_t,
                                                  ea_s, ea_t, cursor, srcs, ea16s);
    wprod_kernel<<<(NLAYER * 2 * QDIM * DIM + NLAYER * QDIM + 255) / 256, 256, 0, stream>>>(
        in_w, root_w, rel_w, rel_b, in_b, wq16, beff);

    dim3 gq(NROWS / 64, QDIM / 64);   // 128 x 6
    dim3 gagg(N_NODES, 2);
    dim3 gattn(BGRAPH, NHEAD, 2);

    for (int i = 0; i < NLAYER; ++i) {
        const _Float16* wq   = wq16   + (size_t)i * 2 * QDIM * DIM;
        const float*    be   = beff   + (size_t)i * QDIM;
        const _Float16* wout = outw16 + (size_t)i * DIM * DIM;
        const float*    bout = out_b  + (size_t)i * DIM;
        const float*    lg   = g_ln   + (size_t)i * DIM;
        const float*    lb   = b_ln   + (size_t)i * DIM;

        agg_kernel<<<gagg, 64, 0, stream>>>(srcs, ea16s, row_start, x16, agg16);
        // qkv = x@(Win Wroot)^T + agg@(Win Wrel)^T + (Win brel + bin)
        qkv2_mfma<<<gq, 256, 0, stream>>>(x16, agg16, wq, be, qb16);
        attn_kernel<<<gattn, 512, 0, stream>>>(qb16, o16);
        gemm_ln_mfma<<<NROWS / 32, 256, 0, stream>>>(o16, wout, bout, lg, lb, x16);
    }

    poolcos_kernel<<<BGRAPH, 256, 0, stream>>>(x16, gate_w, gate_b, out);
}